// Round 7
// baseline (292.719 us; speedup 1.0000x reference)
//
#include <hip/hip_runtime.h>
#include <hip/hip_bf16.h>
#include <stdint.h>

// Problem: B=2, S=2048, D=1024, H=16, DK=64.  M = B*S = 4096.
// Dtype detected at runtime (fp32 vs bf16), canonicalized to bf16.

typedef __attribute__((ext_vector_type(4))) float  f32x4;
typedef __attribute__((ext_vector_type(4))) int    i32x4;
typedef __attribute__((ext_vector_type(8))) __bf16 bf16x8;
typedef __attribute__((ext_vector_type(4))) __bf16 bf16x4;
typedef __attribute__((ext_vector_type(2))) __bf16 bf16x2;

#define MFMA16(a, b, c) __builtin_amdgcn_mfma_f32_16x16x32_bf16((a), (b), (c), 0, 0, 0)

__device__ __forceinline__ void async16(const void* g, void* lds) {
  __builtin_amdgcn_global_load_lds(
      (const __attribute__((address_space(1))) uint32_t*)g,
      (__attribute__((address_space(3))) uint32_t*)lds,
      16, 0, 0);
}

// ---- dtype detector: read w_q as bf16; fp32 mantissa low-halves decode huge.
__global__ void detect_dtype(const uint16_t* __restrict__ w, int* __restrict__ flag) {
  __shared__ int s;
  if (threadIdx.x == 0) s = 0;
  __syncthreads();
  int big = 0;
  for (int i = threadIdx.x; i < 8192; i += 256) {
    uint32_t u = ((uint32_t)w[i]) << 16;
    float f;
    __builtin_memcpy(&f, &u, 4);
    if (fabsf(f) > 1.0f) big = 1;   // xavier bound is 0.054
  }
  if (big) atomicOr(&s, 1);
  __syncthreads();
  if (threadIdx.x == 0) *flag = s;  // 1 = fp32 inputs, 0 = bf16 inputs
}

// ---- canonicalize all float tensors to bf16
struct CvtArgs { const void* src[8]; void* dst[8]; int n[8]; };

__global__ __launch_bounds__(256)
void convert_all(CvtArgs a, const int* __restrict__ flagp) {
  const int t = blockIdx.y;
  const int n = a.n[t];
  const int i0 = (blockIdx.x * 256 + threadIdx.x) * 8;
  if (i0 >= n) return;
  const int f = *flagp;
  if (f) {
    const float* s = (const float*)a.src[t];
    __bf16* d = (__bf16*)a.dst[t];
    bf16x8 v;
#pragma unroll
    for (int j = 0; j < 8; ++j) v[j] = (__bf16)s[i0 + j];
    *(bf16x8*)(d + i0) = v;
  } else {
    const i32x4* s = (const i32x4*)((const char*)a.src[t] + (size_t)i0 * 2);
    i32x4* d = (i32x4*)((char*)a.dst[t] + (size_t)i0 * 2);
    *d = *s;
  }
}

// C = A[4096,1024] @ W[1024,1024]^T  (NT, both K-contiguous, bf16).
// m97-style 128x128 tile, BK=32.  mode 0: QKV layout store; mode 1: bias + flat.
struct GemmArgs {
  const __bf16* A[3]; const __bf16* W[3]; void* C[3]; float scale[3];
  const __bf16* bias; const int* flagp; int mode;
};

__global__ __launch_bounds__(256, 2)
void gemm_nt(GemmArgs ga)
{
  constexpr int K = 1024;
  __shared__ __align__(16) __bf16 As[128 * 32];
  __shared__ __align__(16) __bf16 Bs[128 * 32];

  const int z = blockIdx.z;
  const __bf16* __restrict__ A = ga.A[z];
  const __bf16* __restrict__ W = ga.W[z];
  void* __restrict__ C = ga.C[z];
  const float scale = ga.scale[z];
  const int mode = ga.mode;

  const int tid = threadIdx.x;
  const int lane = tid & 63;
  const int wave = tid >> 6;
  const int l15 = lane & 15;
  const int quad = lane >> 4;
  const int bm = blockIdx.y * 128;
  const int bn = blockIdx.x * 128;
  const int wm = (wave >> 1) * 64;
  const int wn = (wave & 1) * 64;

  f32x4 acc[4][4];
#pragma unroll
  for (int mi = 0; mi < 4; ++mi)
#pragma unroll
    for (int ni = 0; ni < 4; ++ni) {
      f32x4 zz = {0.f, 0.f, 0.f, 0.f};
      acc[mi][ni] = zz;
    }

  for (int kt = 0; kt < K / 32; ++kt) {
    const int k0 = kt * 32;
    __syncthreads();
#pragma unroll
    for (int r = 0; r < 2; ++r) {
      const int chunk = r * 256 + wave * 64 + lane;
      const int row = chunk >> 2, c = chunk & 3;
      async16(A + (size_t)(bm + row) * K + k0 + c * 8, As + (r * 256 + wave * 64) * 8);
      async16(W + (size_t)(bn + row) * K + k0 + c * 8, Bs + (r * 256 + wave * 64) * 8);
    }
    __syncthreads();

    bf16x8 af[4];
    bf16x8 bfr[4];
#pragma unroll
    for (int mi = 0; mi < 4; ++mi)
      af[mi] = *(const bf16x8*)(As + (wm + mi * 16 + l15) * 32 + quad * 8);
#pragma unroll
    for (int ni = 0; ni < 4; ++ni)
      bfr[ni] = *(const bf16x8*)(Bs + (wn + ni * 16 + l15) * 32 + quad * 8);
#pragma unroll
    for (int mi = 0; mi < 4; ++mi)
#pragma unroll
      for (int ni = 0; ni < 4; ++ni)
        acc[mi][ni] = MFMA16(af[mi], bfr[ni], acc[mi][ni]);
  }

  const int f = (mode == 1) ? *ga.flagp : 0;
#pragma unroll
  for (int ni = 0; ni < 4; ++ni) {
    const int n = bn + wn + ni * 16 + l15;
    const float bv = (mode == 1) ? (float)ga.bias[n] : 0.0f;
#pragma unroll
    for (int mi = 0; mi < 4; ++mi) {
#pragma unroll
      for (int r = 0; r < 4; ++r) {
        const int m = bm + wm + mi * 16 + quad * 4 + r;
        const float v = acc[mi][ni][r] * scale + bv;
        if (mode == 0) {
          const int b = m >> 11, s = m & 2047, h = n >> 6, dk = n & 63;
          ((__bf16*)C)[((size_t)(b * 16 + h) * 2048 + s) * 64 + dk] = (__bf16)v;
        } else if (f) {
          ((float*)C)[(size_t)m * 1024 + n] = v;
        } else {
          ((__bf16*)C)[(size_t)m * 1024 + n] = (__bf16)v;
        }
      }
    }
  }
}

// Flash attention, S^T formulation, q-tile 64.  LDS holds ONLY V^T (dbuf) and
// per-wave P strips; Q and K fragments are read directly from global as
// coalesced b128 loads (L2-resident: each K tile reused by 32 q-blocks) with
// register prefetch of the next K tile -> LDS pipe traffic cut ~2.5x (r6 pm:
// attn was LDS-throughput-bound, not chain-bound).
// Q pre-scaled by 1/8.  Q/K/V layout [B*H][2048][64] bf16.
// S^T = K·Q^T: C col=l15=q-local, row=quad*4+r=k.  O^T = V^T·P.
__global__ __launch_bounds__(256, 3)
void attn(const __bf16* __restrict__ Q,
          const __bf16* __restrict__ Kg,
          const __bf16* __restrict__ Vg,
          __bf16* __restrict__ O)
{
  __shared__ __align__(16) __bf16 Vts[2][64][72];    // V^T dbuf; reused as Ot[q][d]
  __shared__ __align__(16) __bf16 PsT[4][16][72];    // per-wave P[q-local][k]

  const int tid = threadIdx.x;
  const int lane = tid & 63;
  const int wave = tid >> 6;
  const int l15 = lane & 15;
  const int quad = lane >> 4;
  const int kp = tid & 31;     // V-transpose k-pair
  const int dg = tid >> 5;     // V-transpose d-group

  // LPT ordering: longest blocks (qt=31) dispatched first
  const int zb = blockIdx.x;
  const int qt = 31 - (zb >> 5);
  const int bh = zb & 31;
  const int q0 = qt * 64;

  const __bf16* Qp = Q + (size_t)bh * 2048 * 64;
  const __bf16* Kp = Kg + (size_t)bh * 2048 * 64;
  const __bf16* Vp = Vg + (size_t)bh * 2048 * 64;

  const int qrow_wl = wave * 16 + l15;   // q local to the 64-tile

  // ---- prologue: Q frags, K tile 0 frags, V tile 0 -- all from global ----
  bf16x8 qf[2], kcur[2][4], knext[2][4];
#pragma unroll
  for (int kc = 0; kc < 2; ++kc)
    qf[kc] = *(const bf16x8*)(Qp + (size_t)(q0 + qrow_wl) * 64 + kc * 32 + quad * 8);
  bf16x8 w0 = *(const bf16x8*)(Vp + (size_t)(2 * kp) * 64 + dg * 8);
  bf16x8 w1 = *(const bf16x8*)(Vp + (size_t)(2 * kp + 1) * 64 + dg * 8);
#pragma unroll
  for (int kc = 0; kc < 2; ++kc)
#pragma unroll
    for (int nt = 0; nt < 4; ++nt)
      kcur[kc][nt] = *(const bf16x8*)(Kp + (size_t)(nt * 16 + l15) * 64 + kc * 32 + quad * 8);

#pragma unroll
  for (int j = 0; j < 8; ++j) {
    bf16x2 pr = { w0[j], w1[j] };
    *(bf16x2*)(&Vts[0][dg * 8 + j][2 * kp]) = pr;
  }
  __syncthreads();   // V^T tile 0 visible

  f32x4 o_[4];
#pragma unroll
  for (int dt = 0; dt < 4; ++dt) {
    f32x4 zz = {0.f, 0.f, 0.f, 0.f};
    o_[dt] = zz;
  }
  float mrow = -1e30f, lrow = 0.0f;

  for (int kt = 0; kt <= qt; ++kt) {
    const int p = kt & 1;
    const bool pf_on = (kt < qt);
    // ---- prefetch tile kt+1: V first (so V^T store waits vmcnt(8), not 0)
    if (pf_on) {
      const int kn = (kt + 1) * 64;
      w0 = *(const bf16x8*)(Vp + (size_t)(kn + 2 * kp) * 64 + dg * 8);
      w1 = *(const bf16x8*)(Vp + (size_t)(kn + 2 * kp + 1) * 64 + dg * 8);
#pragma unroll
      for (int kc = 0; kc < 2; ++kc)
#pragma unroll
        for (int nt = 0; nt < 4; ++nt)
          knext[kc][nt] = *(const bf16x8*)(Kp + (size_t)(kn + nt * 16 + l15) * 64 + kc * 32 + quad * 8);
    }

    // ---- S^T = K·Q^T (K frags in registers)
    f32x4 st[4];
#pragma unroll
    for (int nt = 0; nt < 4; ++nt) {
      f32x4 zz = {0.f, 0.f, 0.f, 0.f};
      st[nt] = zz;
    }
#pragma unroll
    for (int kc = 0; kc < 2; ++kc)
#pragma unroll
      for (int nt = 0; nt < 4; ++nt)
        st[nt] = MFMA16(kcur[kc][nt], qf[kc], st[nt]);

    if (kt == qt) {  // diagonal: mask k > q
#pragma unroll
      for (int nt = 0; nt < 4; ++nt)
#pragma unroll
        for (int r = 0; r < 4; ++r)
          if (nt * 16 + quad * 4 + r > qrow_wl) st[nt][r] = -1e30f;
    }

    // ---- online softmax: per-lane scalar stats (q = qrow_wl)
    float tmax = -1e30f;
#pragma unroll
    for (int nt = 0; nt < 4; ++nt)
#pragma unroll
      for (int r = 0; r < 4; ++r) tmax = fmaxf(tmax, st[nt][r]);
    tmax = fmaxf(tmax, __shfl_xor(tmax, 16, 64));
    tmax = fmaxf(tmax, __shfl_xor(tmax, 32, 64));
    const float mnew = fmaxf(mrow, tmax);
    const float alpha = __expf(mrow - mnew);
    float rs = 0.0f;
#pragma unroll
    for (int nt = 0; nt < 4; ++nt) {
      bf16x4 pd;
#pragma unroll
      for (int r = 0; r < 4; ++r) {
        const float pv = __expf(st[nt][r] - mnew);
        rs += pv;
        pd[r] = (__bf16)pv;
      }
      *(bf16x4*)(&PsT[wave][l15][nt * 16 + quad * 4]) = pd;
    }
    rs += __shfl_xor(rs, 16, 64);
    rs += __shfl_xor(rs, 32, 64);
    lrow = lrow * alpha + rs;
    mrow = mnew;
#pragma unroll
    for (int dt = 0; dt < 4; ++dt) o_[dt] *= alpha;

    // ---- O^T += V^T · P  (P strip is same-wave -> no barrier)
#pragma unroll
    for (int kc = 0; kc < 2; ++kc) {
      bf16x8 pf = *(const bf16x8*)(&PsT[wave][l15][kc * 32 + quad * 8]);
#pragma unroll
      for (int dt = 0; dt < 4; ++dt) {
        bf16x8 vf = *(const bf16x8*)(&Vts[p][dt * 16 + l15][kc * 32 + quad * 8]);
        o_[dt] = MFMA16(vf, pf, o_[dt]);
      }
    }

    // ---- store prefetched V^T into buffer p^1 (its last reader was iter kt-1)
    if (pf_on) {
#pragma unroll
      for (int j = 0; j < 8; ++j) {
        bf16x2 pr = { w0[j], w1[j] };
        *(bf16x2*)(&Vts[p ^ 1][dg * 8 + j][2 * kp]) = pr;
      }
#pragma unroll
      for (int kc = 0; kc < 2; ++kc)
#pragma unroll
        for (int nt = 0; nt < 4; ++nt)
          kcur[kc][nt] = knext[kc][nt];
    }
    __syncthreads();  // publishes V^T p^1 for next iter
  }

  // ---- epilogue: normalize, transpose via LDS (reuse Vts as Ot[q][d])
  __bf16 (*Ot)[72] = (__bf16(*)[72])&Vts[0][0][0];
  const float inv_l = 1.0f / lrow;
#pragma unroll
  for (int dt = 0; dt < 4; ++dt)
#pragma unroll
    for (int r = 0; r < 4; r += 2) {
      bf16x2 pr = { (__bf16)(o_[dt][r] * inv_l),
                    (__bf16)(o_[dt][r + 1] * inv_l) };
      *(bf16x2*)(&Ot[qrow_wl][dt * 16 + quad * 4 + r]) = pr;
    }
  __syncthreads();

  const int b = bh >> 4, h = bh & 15;
#pragma unroll
  for (int t = 0; t < 2; ++t) {
    const int i = t * 256 + tid;
    const int row = i >> 3, c = i & 7;
    f32x4 v = *(const f32x4*)(&Ot[row][c * 8]);
    *(f32x4*)(O + (size_t)(b * 2048 + q0 + row) * 1024 + h * 64 + c * 8) = v;
  }
}

extern "C" void kernel_launch(void* const* d_in, const int* in_sizes, int n_in,
                              void* d_out, int out_size, void* d_ws, size_t ws_size,
                              hipStream_t stream) {
  char* ws = (char*)d_ws;
  int* flag = (int*)ws;
  __bf16* Xc0 = (__bf16*)(ws + (1u << 20));    // 8 MB each
  __bf16* Xc1 = (__bf16*)(ws + (9u << 20));
  __bf16* Xc2 = (__bf16*)(ws + (17u << 20));
  __bf16* Wc0 = (__bf16*)(ws + (25u << 20));   // 2 MB each
  __bf16* Wc1 = (__bf16*)(ws + (27u << 20));
  __bf16* Wc2 = (__bf16*)(ws + (29u << 20));
  __bf16* Wc3 = (__bf16*)(ws + (31u << 20));
  __bf16* bc  = (__bf16*)(ws + (33u << 20));
  __bf16* Qw  = (__bf16*)(ws + (34u << 20));   // 8 MB each, [B*H][S][64]
  __bf16* Kw  = (__bf16*)(ws + (42u << 20));
  __bf16* Vw  = (__bf16*)(ws + (50u << 20));
  __bf16* Aw  = Xc0;                           // X dead after projections

  detect_dtype<<<1, 256, 0, stream>>>((const uint16_t*)d_in[4], flag);

  CvtArgs ca;
  ca.src[0] = d_in[0]; ca.dst[0] = Xc0; ca.n[0] = 4194304;
  ca.src[1] = d_in[1]; ca.dst[1] = Xc1; ca.n[1] = 4194304;
  ca.src[2] = d_in[2]; ca.dst[2] = Xc2; ca.n[2] = 4194304;
  ca.src[3] = d_in[4]; ca.dst[3] = Wc0; ca.n[3] = 1048576;
  ca.src[4] = d_in[5]; ca.dst[4] = Wc1; ca.n[4] = 1048576;
  ca.src[5] = d_in[6]; ca.dst[5] = Wc2; ca.n[5] = 1048576;
  ca.src[6] = d_in[7]; ca.dst[6] = Wc3; ca.n[6] = 1048576;
  ca.src[7] = d_in[8]; ca.dst[7] = bc;  ca.n[7] = 1024;
  convert_all<<<dim3(2048, 8), 256, 0, stream>>>(ca, flag);

  // fused Q/K/V projections (scores scale 1/8 folded into Q)
  GemmArgs g0;
  g0.A[0] = Xc0; g0.W[0] = Wc0; g0.C[0] = Qw; g0.scale[0] = 0.125f;
  g0.A[1] = Xc1; g0.W[1] = Wc1; g0.C[1] = Kw; g0.scale[1] = 1.0f;
  g0.A[2] = Xc2; g0.W[2] = Wc2; g0.C[2] = Vw; g0.scale[2] = 1.0f;
  g0.bias = nullptr; g0.flagp = flag; g0.mode = 0;
  gemm_nt<<<dim3(8, 32, 3), 256, 0, stream>>>(g0);

  attn<<<dim3(1024), 256, 0, stream>>>(Qw, Kw, Vw, Aw);

  GemmArgs g1;
  g1.A[0] = Aw; g1.W[0] = Wc3; g1.C[0] = d_out; g1.scale[0] = 1.0f;
  g1.A[1] = nullptr; g1.W[1] = nullptr; g1.C[1] = nullptr; g1.scale[1] = 0.f;
  g1.A[2] = nullptr; g1.W[2] = nullptr; g1.C[2] = nullptr; g1.scale[2] = 0.f;
  g1.bias = bc; g1.flagp = flag; g1.mode = 1;
  gemm_nt<<<dim3(8, 32, 1), 256, 0, stream>>>(g1);
}

// Round 8
// 247.951 us; speedup vs baseline: 1.1806x; 1.1806x over previous
//
#include <hip/hip_runtime.h>
#include <hip/hip_bf16.h>
#include <stdint.h>

// Problem: B=2, S=2048, D=1024, H=16, DK=64.  M = B*S = 4096.
// Dtype detected at runtime (fp32 vs bf16); bf16 inputs are consumed in-place
// (no copy), fp32 inputs are converted once into d_ws.

typedef __attribute__((ext_vector_type(4))) float  f32x4;
typedef __attribute__((ext_vector_type(4))) int    i32x4;
typedef __attribute__((ext_vector_type(8))) __bf16 bf16x8;
typedef __attribute__((ext_vector_type(4))) __bf16 bf16x4;
typedef __attribute__((ext_vector_type(2))) __bf16 bf16x2;

#define MFMA16(a, b, c) __builtin_amdgcn_mfma_f32_16x16x32_bf16((a), (b), (c), 0, 0, 0)

__device__ __forceinline__ void async16(const void* g, void* lds) {
  __builtin_amdgcn_global_load_lds(
      (const __attribute__((address_space(1))) uint32_t*)g,
      (__attribute__((address_space(3))) uint32_t*)lds,
      16, 0, 0);
}

// XOR-swizzled LDS tile (row-major, 64 bf16 cols = 8 chunks of 16B): element
// (row, col/8) stored at chunk row*8 + ((col/8) ^ (row&7)).  ~2-way (free).
__device__ __forceinline__ bf16x8 lds_swz_read(const __bf16* base, int row, int cchunk) {
  const int sw = cchunk ^ (row & 7);
  return *(const bf16x8*)((const char*)base + row * 128 + sw * 16);
}

// ---- dtype detector: read w_q as bf16; fp32 mantissa low-halves decode huge.
__global__ void detect_dtype(const uint16_t* __restrict__ w, int* __restrict__ flag) {
  __shared__ int s;
  if (threadIdx.x == 0) s = 0;
  __syncthreads();
  int big = 0;
  for (int i = threadIdx.x; i < 8192; i += 256) {
    uint32_t u = ((uint32_t)w[i]) << 16;
    float f;
    __builtin_memcpy(&f, &u, 4);
    if (fabsf(f) > 1.0f) big = 1;   // xavier bound is 0.054
  }
  if (big) atomicOr(&s, 1);
  __syncthreads();
  if (threadIdx.x == 0) *flag = s;  // 1 = fp32 inputs, 0 = bf16 inputs
}

// ---- fp32 -> bf16 conversion (only runs when inputs are fp32)
struct CvtArgs { const void* src[8]; void* dst[8]; int n[8]; };

__global__ __launch_bounds__(256)
void convert_all(CvtArgs a, const int* __restrict__ flagp) {
  if (*flagp == 0) return;   // bf16 inputs: consumers read d_in directly
  const int t = blockIdx.y;
  const int n = a.n[t];
  const int i0 = (blockIdx.x * 256 + threadIdx.x) * 8;
  if (i0 >= n) return;
  const float* s = (const float*)a.src[t];
  __bf16* d = (__bf16*)a.dst[t];
  bf16x8 v;
#pragma unroll
  for (int j = 0; j < 8; ++j) v[j] = (__bf16)s[i0 + j];
  *(bf16x8*)(d + i0) = v;
}

// C = A[4096,1024] @ W[1024,1024]^T  (NT, both K-contiguous, bf16).
// m97-style 128x128 tile, BK=32.  mode 0: QKV layout store; mode 1: bias + flat.
// Pointers selected device-side per dtype flag (Acvt/Wcvt when fp32-converted).
struct GemmArgs {
  const __bf16* A[3];    const __bf16* W[3];      // bf16-in-place pointers
  const __bf16* Acvt[3]; const __bf16* Wcvt[3];   // converted-copy pointers
  void* C[3]; float scale[3];
  const __bf16* bias; const __bf16* biascvt;
  const int* flagp; int mode;
};

__global__ __launch_bounds__(256, 2)
void gemm_nt(GemmArgs ga)
{
  constexpr int K = 1024;
  __shared__ __align__(16) __bf16 As[128 * 32];
  __shared__ __align__(16) __bf16 Bs[128 * 32];

  const int z = blockIdx.z;
  const int f = *ga.flagp;
  const __bf16* __restrict__ A = f ? ga.Acvt[z] : ga.A[z];
  const __bf16* __restrict__ W = f ? ga.Wcvt[z] : ga.W[z];
  void* __restrict__ C = ga.C[z];
  const float scale = ga.scale[z];
  const int mode = ga.mode;

  const int tid = threadIdx.x;
  const int lane = tid & 63;
  const int wave = tid >> 6;
  const int l15 = lane & 15;
  const int quad = lane >> 4;
  const int bm = blockIdx.y * 128;
  const int bn = blockIdx.x * 128;
  const int wm = (wave >> 1) * 64;
  const int wn = (wave & 1) * 64;

  f32x4 acc[4][4];
#pragma unroll
  for (int mi = 0; mi < 4; ++mi)
#pragma unroll
    for (int ni = 0; ni < 4; ++ni) {
      f32x4 zz = {0.f, 0.f, 0.f, 0.f};
      acc[mi][ni] = zz;
    }

  for (int kt = 0; kt < K / 32; ++kt) {
    const int k0 = kt * 32;
    __syncthreads();
#pragma unroll
    for (int r = 0; r < 2; ++r) {
      const int chunk = r * 256 + wave * 64 + lane;
      const int row = chunk >> 2, c = chunk & 3;
      async16(A + (size_t)(bm + row) * K + k0 + c * 8, As + (r * 256 + wave * 64) * 8);
      async16(W + (size_t)(bn + row) * K + k0 + c * 8, Bs + (r * 256 + wave * 64) * 8);
    }
    __syncthreads();

    bf16x8 af[4];
    bf16x8 bfr[4];
#pragma unroll
    for (int mi = 0; mi < 4; ++mi)
      af[mi] = *(const bf16x8*)(As + (wm + mi * 16 + l15) * 32 + quad * 8);
#pragma unroll
    for (int ni = 0; ni < 4; ++ni)
      bfr[ni] = *(const bf16x8*)(Bs + (wn + ni * 16 + l15) * 32 + quad * 8);
#pragma unroll
    for (int mi = 0; mi < 4; ++mi)
#pragma unroll
      for (int ni = 0; ni < 4; ++ni)
        acc[mi][ni] = MFMA16(af[mi], bfr[ni], acc[mi][ni]);
  }

  const __bf16* bias = (mode == 1) ? (f ? ga.biascvt : ga.bias) : nullptr;
#pragma unroll
  for (int ni = 0; ni < 4; ++ni) {
    const int n = bn + wn + ni * 16 + l15;
    const float bv = (mode == 1) ? (float)bias[n] : 0.0f;
#pragma unroll
    for (int mi = 0; mi < 4; ++mi) {
#pragma unroll
      for (int r = 0; r < 4; ++r) {
        const int m = bm + wm + mi * 16 + quad * 4 + r;
        const float v = acc[mi][ni][r] * scale + bv;
        if (mode == 0) {
          const int b = m >> 11, s = m & 2047, h = n >> 6, dk = n & 63;
          ((__bf16*)C)[((size_t)(b * 16 + h) * 2048 + s) * 64 + dk] = (__bf16)v;
        } else if (f) {
          ((float*)C)[(size_t)m * 1024 + n] = v;
        } else {
          ((__bf16*)C)[(size_t)m * 1024 + n] = (__bf16)v;
        }
      }
    }
  }
}

// Flash attention, S^T formulation, q-tile 64, KEY-TILE 128 per iteration:
// barriers / staging-drains / softmax shuffle chains amortized over 2x keys
// (r5 pm: per-iter fixed costs dominate at ~2000cyc/iter with all pipes <35%).
// K staged via async16 (staging-ordered, 8x128B segments -- r7 pm: direct
// frag loads from global scatter 16x64B and choke TA).  LDS: K 16KB +
// V^T 17.4KB + P 17.4KB = 51.2KB -> 3 blocks/CU.
// Q pre-scaled by 1/8.  Q/K/V layout [B*H][2048][64] bf16.
// S^T = K·Q^T: C col=l15=q-local, row=quad*4+r=k-in-16tile.  O^T = V^T·P.
__global__ __launch_bounds__(256, 3)
void attn(const __bf16* __restrict__ Q,
          const __bf16* __restrict__ Kg,
          const __bf16* __restrict__ Vg,
          __bf16* __restrict__ O)
{
  __shared__ __align__(16) __bf16 Ks[128 * 64];     // swizzled K tile (16 KB)
  __shared__ __align__(16) __bf16 Vts[64][136];     // V^T [d][k0..127]; reused as Ot
  __shared__ __align__(16) __bf16 PsT[4][16][136];  // per-wave P[q-local][k]

  const int tid = threadIdx.x;
  const int lane = tid & 63;
  const int wave = tid >> 6;
  const int l15 = lane & 15;
  const int quad = lane >> 4;

  // LPT ordering: longest blocks (qt=31) dispatched first
  const int zb = blockIdx.x;
  const int qt = 31 - (zb >> 5);
  const int bh = zb & 31;
  const int q0 = qt * 64;
  const int nIter = (qt >> 1) + 1;

  const __bf16* Qp = Q + (size_t)bh * 2048 * 64;
  const __bf16* Kp = Kg + (size_t)bh * 2048 * 64;
  const __bf16* Vp = Vg + (size_t)bh * 2048 * 64;

  const int qrow_wl = wave * 16 + l15;   // q local to the 64-tile

  // Q fragments once from global (one-time; coalescing cost amortized)
  bf16x8 qf[2];
#pragma unroll
  for (int kc = 0; kc < 2; ++kc)
    qf[kc] = *(const bf16x8*)(Qp + (size_t)(q0 + qrow_wl) * 64 + kc * 32 + quad * 8);

  f32x4 o_[4];
#pragma unroll
  for (int dt = 0; dt < 4; ++dt) {
    f32x4 zz = {0.f, 0.f, 0.f, 0.f};
    o_[dt] = zz;
  }
  float mrow = -1e30f, lrow = 0.0f;

  for (int ktt = 0; ktt < nIter; ++ktt) {
    const int k0 = ktt * 128;
    __syncthreads();   // previous iter done with Ks/Vts
    // ---- stage K tile 128x64 (swizzled, async): 1024 chunks, 4/thread
#pragma unroll
    for (int r = 0; r < 4; ++r) {
      const int chunk = r * 256 + tid;
      const int row = chunk >> 3, c = (chunk & 7) ^ (row & 7);
      async16(Kp + (size_t)(k0 + row) * 64 + c * 8,
              (char*)Ks + (r * 256 + wave * 64) * 16);
    }
    // ---- stage V^T (paired-k bf16x2 stores, 2-way free): 512 tasks, 2/thread
#pragma unroll
    for (int rr = 0; rr < 2; ++rr) {
      const int task = rr * 256 + tid;
      const int pp = task & 63, dgg = task >> 6;
      bf16x8 v0 = *(const bf16x8*)(Vp + (size_t)(k0 + 2 * pp) * 64 + dgg * 8);
      bf16x8 v1 = *(const bf16x8*)(Vp + (size_t)(k0 + 2 * pp + 1) * 64 + dgg * 8);
#pragma unroll
      for (int j = 0; j < 8; ++j) {
        bf16x2 pr = { v0[j], v1[j] };
        *(bf16x2*)(&Vts[dgg * 8 + j][2 * pp]) = pr;
      }
    }
    __syncthreads();

    // ---- S^T = K·Q^T over 8 k-subtiles
    f32x4 st[8];
#pragma unroll
    for (int nt = 0; nt < 8; ++nt) {
      f32x4 zz = {0.f, 0.f, 0.f, 0.f};
      st[nt] = zz;
    }
#pragma unroll
    for (int kc = 0; kc < 2; ++kc)
#pragma unroll
      for (int nt = 0; nt < 8; ++nt) {
        bf16x8 kf = lds_swz_read(Ks, nt * 16 + l15, kc * 4 + quad);
        st[nt] = MFMA16(kf, qf[kc], st[nt]);
      }

    if (ktt == (qt >> 1)) {  // last tile: mask keys > q (also masks overshoot)
#pragma unroll
      for (int nt = 0; nt < 8; ++nt)
#pragma unroll
        for (int r = 0; r < 4; ++r)
          if (k0 + nt * 16 + quad * 4 + r > q0 + qrow_wl) st[nt][r] = -1e30f;
    }

    // ---- online softmax: per-lane scalar stats (q = qrow_wl)
    float tmax = -1e30f;
#pragma unroll
    for (int nt = 0; nt < 8; ++nt)
#pragma unroll
      for (int r = 0; r < 4; ++r) tmax = fmaxf(tmax, st[nt][r]);
    tmax = fmaxf(tmax, __shfl_xor(tmax, 16, 64));
    tmax = fmaxf(tmax, __shfl_xor(tmax, 32, 64));
    const float mnew = fmaxf(mrow, tmax);
    const float alpha = __expf(mrow - mnew);
    float rs = 0.0f;
#pragma unroll
    for (int nt = 0; nt < 8; ++nt) {
      bf16x4 pd;
#pragma unroll
      for (int r = 0; r < 4; ++r) {
        const float pv = __expf(st[nt][r] - mnew);
        rs += pv;
        pd[r] = (__bf16)pv;
      }
      *(bf16x4*)(&PsT[wave][l15][nt * 16 + quad * 4]) = pd;
    }
    rs += __shfl_xor(rs, 16, 64);
    rs += __shfl_xor(rs, 32, 64);
    lrow = lrow * alpha + rs;
    mrow = mnew;
#pragma unroll
    for (int dt = 0; dt < 4; ++dt) o_[dt] *= alpha;

    // ---- O^T += V^T · P  (P strip same-wave -> no barrier; k runs 0..127)
#pragma unroll
    for (int kc = 0; kc < 4; ++kc) {
      bf16x8 pf = *(const bf16x8*)(&PsT[wave][l15][kc * 32 + quad * 8]);
#pragma unroll
      for (int dt = 0; dt < 4; ++dt) {
        bf16x8 vf = *(const bf16x8*)(&Vts[dt * 16 + l15][kc * 32 + quad * 8]);
        o_[dt] = MFMA16(vf, pf, o_[dt]);
      }
    }
  }

  // ---- epilogue: normalize, transpose via LDS (reuse Vts as Ot[64][72])
  __syncthreads();
  __bf16 (*Ot)[72] = (__bf16(*)[72])&Vts[0][0];
  const float inv_l = 1.0f / lrow;
#pragma unroll
  for (int dt = 0; dt < 4; ++dt)
#pragma unroll
    for (int r = 0; r < 4; r += 2) {
      bf16x2 pr = { (__bf16)(o_[dt][r] * inv_l),
                    (__bf16)(o_[dt][r + 1] * inv_l) };
      *(bf16x2*)(&Ot[qrow_wl][dt * 16 + quad * 4 + r]) = pr;
    }
  __syncthreads();

  const int b = bh >> 4, h = bh & 15;
#pragma unroll
  for (int t = 0; t < 2; ++t) {
    const int i = t * 256 + tid;
    const int row = i >> 3, c = i & 7;
    f32x4 v = *(const f32x4*)(&Ot[row][c * 8]);
    *(f32x4*)(O + (size_t)(b * 2048 + q0 + row) * 1024 + h * 64 + c * 8) = v;
  }
}

extern "C" void kernel_launch(void* const* d_in, const int* in_sizes, int n_in,
                              void* d_out, int out_size, void* d_ws, size_t ws_size,
                              hipStream_t stream) {
  char* ws = (char*)d_ws;
  int* flag = (int*)ws;
  __bf16* Xc0 = (__bf16*)(ws + (1u << 20));    // 8 MB each (fp32-cvt targets)
  __bf16* Xc1 = (__bf16*)(ws + (9u << 20));
  __bf16* Xc2 = (__bf16*)(ws + (17u << 20));
  __bf16* Wc0 = (__bf16*)(ws + (25u << 20));   // 2 MB each
  __bf16* Wc1 = (__bf16*)(ws + (27u << 20));
  __bf16* Wc2 = (__bf16*)(ws + (29u << 20));
  __bf16* Wc3 = (__bf16*)(ws + (31u << 20));
  __bf16* bc  = (__bf16*)(ws + (33u << 20));
  __bf16* Qw  = (__bf16*)(ws + (34u << 20));   // 8 MB each, [B*H][S][64]
  __bf16* Kw  = (__bf16*)(ws + (42u << 20));
  __bf16* Vw  = (__bf16*)(ws + (50u << 20));
  __bf16* Aw  = (__bf16*)(ws + (58u << 20));   // attn output [4096][1024]

  detect_dtype<<<1, 256, 0, stream>>>((const uint16_t*)d_in[4], flag);

  CvtArgs ca;
  ca.src[0] = d_in[0]; ca.dst[0] = Xc0; ca.n[0] = 4194304;
  ca.src[1] = d_in[1]; ca.dst[1] = Xc1; ca.n[1] = 4194304;
  ca.src[2] = d_in[2]; ca.dst[2] = Xc2; ca.n[2] = 4194304;
  ca.src[3] = d_in[4]; ca.dst[3] = Wc0; ca.n[3] = 1048576;
  ca.src[4] = d_in[5]; ca.dst[4] = Wc1; ca.n[4] = 1048576;
  ca.src[5] = d_in[6]; ca.dst[5] = Wc2; ca.n[5] = 1048576;
  ca.src[6] = d_in[7]; ca.dst[6] = Wc3; ca.n[6] = 1048576;
  ca.src[7] = d_in[8]; ca.dst[7] = bc;  ca.n[7] = 1024;
  convert_all<<<dim3(2048, 8), 256, 0, stream>>>(ca, flag);

  // fused Q/K/V projections (scores scale 1/8 folded into Q)
  GemmArgs g0;
  g0.A[0] = (const __bf16*)d_in[0]; g0.Acvt[0] = Xc0;
  g0.A[1] = (const __bf16*)d_in[1]; g0.Acvt[1] = Xc1;
  g0.A[2] = (const __bf16*)d_in[2]; g0.Acvt[2] = Xc2;
  g0.W[0] = (const __bf16*)d_in[4]; g0.Wcvt[0] = Wc0;
  g0.W[1] = (const __bf16*)d_in[5]; g0.Wcvt[1] = Wc1;
  g0.W[2] = (const __bf16*)d_in[6]; g0.Wcvt[2] = Wc2;
  g0.C[0] = Qw; g0.scale[0] = 0.125f;
  g0.C[1] = Kw; g0.scale[1] = 1.0f;
  g0.C[2] = Vw; g0.scale[2] = 1.0f;
  g0.bias = nullptr; g0.biascvt = nullptr; g0.flagp = flag; g0.mode = 0;
  gemm_nt<<<dim3(8, 32, 3), 256, 0, stream>>>(g0);

  attn<<<dim3(1024), 256, 0, stream>>>(Qw, Kw, Vw, Aw);

  GemmArgs g1;
  g1.A[0] = Aw; g1.Acvt[0] = Aw;
  g1.A[1] = nullptr; g1.Acvt[1] = nullptr;
  g1.A[2] = nullptr; g1.Acvt[2] = nullptr;
  g1.W[0] = (const __bf16*)d_in[7]; g1.Wcvt[0] = Wc3;
  g1.W[1] = nullptr; g1.Wcvt[1] = nullptr;
  g1.W[2] = nullptr; g1.Wcvt[2] = nullptr;
  g1.C[0] = d_out; g1.scale[0] = 1.0f;
  g1.C[1] = nullptr; g1.scale[1] = 0.f;
  g1.C[2] = nullptr; g1.scale[2] = 0.f;
  g1.bias = (const __bf16*)d_in[8]; g1.biascvt = bc;
  g1.flagp = flag; g1.mode = 1;
  gemm_nt<<<dim3(8, 32, 1), 256, 0, stream>>>(g1);
}

// Round 9
// 241.205 us; speedup vs baseline: 1.2136x; 1.0280x over previous
//
#include <hip/hip_runtime.h>
#include <hip/hip_bf16.h>
#include <stdint.h>

// Problem: B=2, S=2048, D=1024, H=16, DK=64.  M = B*S = 4096.
// Inputs detected fp32 (flag=1) vs bf16; fp32 converted once into d_ws.

typedef __attribute__((ext_vector_type(4))) float  f32x4;
typedef __attribute__((ext_vector_type(4))) int    i32x4;
typedef __attribute__((ext_vector_type(8))) __bf16 bf16x8;
typedef __attribute__((ext_vector_type(4))) __bf16 bf16x4;
typedef __attribute__((ext_vector_type(2))) __bf16 bf16x2;

#define MFMA16(a, b, c) __builtin_amdgcn_mfma_f32_16x16x32_bf16((a), (b), (c), 0, 0, 0)

__device__ __forceinline__ void async16(const void* g, void* lds) {
  __builtin_amdgcn_global_load_lds(
      (const __attribute__((address_space(1))) uint32_t*)g,
      (__attribute__((address_space(3))) uint32_t*)lds,
      16, 0, 0);
}

// XOR-swizzled LDS tile (row-major, 64 bf16 cols = 8 chunks of 16B)
__device__ __forceinline__ bf16x8 lds_swz_read(const __bf16* base, int row, int cchunk) {
  const int sw = cchunk ^ (row & 7);
  return *(const bf16x8*)((const char*)base + row * 128 + sw * 16);
}

// ---- dtype detector: read w_q as bf16; fp32 mantissa low-halves decode huge.
__global__ void detect_dtype(const uint16_t* __restrict__ w, int* __restrict__ flag) {
  __shared__ int s;
  if (threadIdx.x == 0) s = 0;
  __syncthreads();
  int big = 0;
  for (int i = threadIdx.x; i < 8192; i += 256) {
    uint32_t u = ((uint32_t)w[i]) << 16;
    float f;
    __builtin_memcpy(&f, &u, 4);
    if (fabsf(f) > 1.0f) big = 1;   // xavier bound is 0.054
  }
  if (big) atomicOr(&s, 1);
  __syncthreads();
  if (threadIdx.x == 0) *flag = s;  // 1 = fp32 inputs, 0 = bf16 inputs
}

// ---- fp32 -> bf16 conversion (only runs when inputs are fp32)
struct CvtArgs { const void* src[8]; void* dst[8]; int n[8]; };

__global__ __launch_bounds__(256)
void convert_all(CvtArgs a, const int* __restrict__ flagp) {
  if (*flagp == 0) return;
  const int t = blockIdx.y;
  const int n = a.n[t];
  const int i0 = (blockIdx.x * 256 + threadIdx.x) * 8;
  if (i0 >= n) return;
  const float* s = (const float*)a.src[t];
  __bf16* d = (__bf16*)a.dst[t];
  bf16x8 v;
#pragma unroll
  for (int j = 0; j < 8; ++j) v[j] = (__bf16)s[i0 + j];
  *(bf16x8*)(d + i0) = v;
}

// C = A[4096,1024] @ W[1024,1024]^T  (NT, both K-contiguous, bf16).
// 128x128 tile, BK=32.  XCD-swizzled block mapping (r9): each XCD owns 4
// contiguous m-panels so A-panel re-reads hit its own L2.
// Epilogue (r9): C tile staged through LDS -> 16B coalesced global stores
// (was 64x 2B scatter/thread -> WRITE_SIZE 60MB RMW).
struct GemmArgs {
  const __bf16* A[3];    const __bf16* W[3];
  const __bf16* Acvt[3]; const __bf16* Wcvt[3];
  void* C[3]; float scale[3];
  const __bf16* bias; const __bf16* biascvt;
  const int* flagp; int mode;
};

__global__ __launch_bounds__(256, 3)
void gemm_nt(GemmArgs ga)
{
  constexpr int K = 1024;
  __shared__ __align__(16) __bf16 smem[8704];   // staging 16KB; epilogue 64x136
  __bf16* As = smem;            // 128x32
  __bf16* Bs = smem + 4096;     // 128x32

  // XCD-aware decode: id%8 = XCD (dispatch round-robin); m-panel = xcd*4+j2
  const int id = blockIdx.x + (blockIdx.y << 3) + (blockIdx.z << 8);
  const int mb = (id & 7) * 4 + ((id >> 3) & 3);
  const int rest = id >> 5;
  const int nb = rest & 7;
  const int z = rest >> 3;

  const int f = *ga.flagp;
  const __bf16* __restrict__ A = f ? ga.Acvt[z] : ga.A[z];
  const __bf16* __restrict__ W = f ? ga.Wcvt[z] : ga.W[z];
  void* __restrict__ C = ga.C[z];
  const float scale = ga.scale[z];
  const int mode = ga.mode;

  const int tid = threadIdx.x;
  const int lane = tid & 63;
  const int wave = tid >> 6;
  const int l15 = lane & 15;
  const int quad = lane >> 4;
  const int bm = mb * 128;
  const int bn = nb * 128;
  const int wm = (wave >> 1) * 64;
  const int wn = (wave & 1) * 64;

  f32x4 acc[4][4];
#pragma unroll
  for (int mi = 0; mi < 4; ++mi)
#pragma unroll
    for (int ni = 0; ni < 4; ++ni) {
      f32x4 zz = {0.f, 0.f, 0.f, 0.f};
      acc[mi][ni] = zz;
    }

  for (int kt = 0; kt < K / 32; ++kt) {
    const int k0 = kt * 32;
    __syncthreads();
#pragma unroll
    for (int r = 0; r < 2; ++r) {
      const int chunk = r * 256 + wave * 64 + lane;
      const int row = chunk >> 2, c = chunk & 3;
      async16(A + (size_t)(bm + row) * K + k0 + c * 8, As + (r * 256 + wave * 64) * 8);
      async16(W + (size_t)(bn + row) * K + k0 + c * 8, Bs + (r * 256 + wave * 64) * 8);
    }
    __syncthreads();

    bf16x8 af[4];
    bf16x8 bfr[4];
#pragma unroll
    for (int mi = 0; mi < 4; ++mi)
      af[mi] = *(const bf16x8*)(As + (wm + mi * 16 + l15) * 32 + quad * 8);
#pragma unroll
    for (int ni = 0; ni < 4; ++ni)
      bfr[ni] = *(const bf16x8*)(Bs + (wn + ni * 16 + l15) * 32 + quad * 8);
#pragma unroll
    for (int mi = 0; mi < 4; ++mi)
#pragma unroll
      for (int ni = 0; ni < 4; ++ni)
        acc[mi][ni] = MFMA16(af[mi], bfr[ni], acc[mi][ni]);
  }

  // ---- coalesced epilogue via LDS, two 64-row passes ----
  float bv[4] = {0.f, 0.f, 0.f, 0.f};
  if (mode == 1) {
    const __bf16* bias = f ? ga.biascvt : ga.bias;
#pragma unroll
    for (int ni = 0; ni < 4; ++ni) bv[ni] = (float)bias[bn + wn + ni * 16 + l15];
  }
  __bf16 (*Cs)[136] = (__bf16(*)[136])smem;

#pragma unroll
  for (int pass = 0; pass < 2; ++pass) {
    __syncthreads();   // staging (pass 0) / previous pass reads (pass 1) done
    if ((wave >> 1) == pass) {
#pragma unroll
      for (int mi = 0; mi < 4; ++mi)
#pragma unroll
        for (int ni = 0; ni < 4; ++ni)
#pragma unroll
          for (int r = 0; r < 4; ++r)
            Cs[mi * 16 + quad * 4 + r][wn + ni * 16 + l15] =
                (__bf16)(acc[mi][ni][r] * scale + bv[ni]);
    }
    __syncthreads();

    if (mode == 0) {
      // rows are (b,h,s) segments of 128B: seg = rowl*2 + head-half
#pragma unroll
      for (int it = 0; it < 4; ++it) {
        const int cid = it * 256 + tid;           // 1024 chunks of 16B
        const int off = cid & 7, seg = cid >> 3;
        const int hl = seg & 1, rowl = seg >> 1;
        f32x4 v = *(const f32x4*)(&Cs[rowl][hl * 64 + off * 8]);
        const int m = bm + pass * 64 + rowl;
        const int b = m >> 11, s = m & 2047;
        const int h = (bn >> 6) + hl;
        *(f32x4*)((__bf16*)C + ((size_t)(b * 16 + h) * 2048 + s) * 64 + off * 8) = v;
      }
    } else if (f) {
#pragma unroll
      for (int it = 0; it < 4; ++it) {
        const int cid = it * 256 + tid;           // 1024 chunks of 8 bf16
        const int off = cid & 15, rowl = cid >> 4;
        bf16x8 vb = *(const bf16x8*)(&Cs[rowl][off * 8]);
        const int m = bm + pass * 64 + rowl;
        float* dst = (float*)C + (size_t)m * 1024 + bn + off * 8;
        f32x4 lo, hi;
#pragma unroll
        for (int j = 0; j < 4; ++j) { lo[j] = (float)vb[j]; hi[j] = (float)vb[4 + j]; }
        *(f32x4*)dst = lo;
        *(f32x4*)(dst + 4) = hi;
      }
    } else {
#pragma unroll
      for (int it = 0; it < 4; ++it) {
        const int cid = it * 256 + tid;
        const int off = cid & 15, rowl = cid >> 4;
        bf16x8 vb = *(const bf16x8*)(&Cs[rowl][off * 8]);
        const int m = bm + pass * 64 + rowl;
        *(bf16x8*)((__bf16*)C + (size_t)m * 1024 + bn + off * 8) = vb;
      }
    }
  }
}

// Flash attention (r8 structure, unchanged): S^T formulation, q-tile 64,
// key-tile 128/iter; K staged via async16, V^T + per-wave P strips in LDS.
__global__ __launch_bounds__(256, 3)
void attn(const __bf16* __restrict__ Q,
          const __bf16* __restrict__ Kg,
          const __bf16* __restrict__ Vg,
          __bf16* __restrict__ O)
{
  __shared__ __align__(16) __bf16 Ks[128 * 64];
  __shared__ __align__(16) __bf16 Vts[64][136];
  __shared__ __align__(16) __bf16 PsT[4][16][136];

  const int tid = threadIdx.x;
  const int lane = tid & 63;
  const int wave = tid >> 6;
  const int l15 = lane & 15;
  const int quad = lane >> 4;

  const int zb = blockIdx.x;
  const int qt = 31 - (zb >> 5);
  const int bh = zb & 31;
  const int q0 = qt * 64;
  const int nIter = (qt >> 1) + 1;

  const __bf16* Qp = Q + (size_t)bh * 2048 * 64;
  const __bf16* Kp = Kg + (size_t)bh * 2048 * 64;
  const __bf16* Vp = Vg + (size_t)bh * 2048 * 64;

  const int qrow_wl = wave * 16 + l15;

  bf16x8 qf[2];
#pragma unroll
  for (int kc = 0; kc < 2; ++kc)
    qf[kc] = *(const bf16x8*)(Qp + (size_t)(q0 + qrow_wl) * 64 + kc * 32 + quad * 8);

  f32x4 o_[4];
#pragma unroll
  for (int dt = 0; dt < 4; ++dt) {
    f32x4 zz = {0.f, 0.f, 0.f, 0.f};
    o_[dt] = zz;
  }
  float mrow = -1e30f, lrow = 0.0f;

  for (int ktt = 0; ktt < nIter; ++ktt) {
    const int k0 = ktt * 128;
    __syncthreads();
#pragma unroll
    for (int r = 0; r < 4; ++r) {
      const int chunk = r * 256 + tid;
      const int row = chunk >> 3, c = (chunk & 7) ^ (row & 7);
      async16(Kp + (size_t)(k0 + row) * 64 + c * 8,
              (char*)Ks + (r * 256 + wave * 64) * 16);
    }
#pragma unroll
    for (int rr = 0; rr < 2; ++rr) {
      const int task = rr * 256 + tid;
      const int pp = task & 63, dgg = task >> 6;
      bf16x8 v0 = *(const bf16x8*)(Vp + (size_t)(k0 + 2 * pp) * 64 + dgg * 8);
      bf16x8 v1 = *(const bf16x8*)(Vp + (size_t)(k0 + 2 * pp + 1) * 64 + dgg * 8);
#pragma unroll
      for (int j = 0; j < 8; ++j) {
        bf16x2 pr = { v0[j], v1[j] };
        *(bf16x2*)(&Vts[dgg * 8 + j][2 * pp]) = pr;
      }
    }
    __syncthreads();

    f32x4 st[8];
#pragma unroll
    for (int nt = 0; nt < 8; ++nt) {
      f32x4 zz = {0.f, 0.f, 0.f, 0.f};
      st[nt] = zz;
    }
#pragma unroll
    for (int kc = 0; kc < 2; ++kc)
#pragma unroll
      for (int nt = 0; nt < 8; ++nt) {
        bf16x8 kf = lds_swz_read(Ks, nt * 16 + l15, kc * 4 + quad);
        st[nt] = MFMA16(kf, qf[kc], st[nt]);
      }

    if (ktt == (qt >> 1)) {
#pragma unroll
      for (int nt = 0; nt < 8; ++nt)
#pragma unroll
        for (int r = 0; r < 4; ++r)
          if (k0 + nt * 16 + quad * 4 + r > q0 + qrow_wl) st[nt][r] = -1e30f;
    }

    float tmax = -1e30f;
#pragma unroll
    for (int nt = 0; nt < 8; ++nt)
#pragma unroll
      for (int r = 0; r < 4; ++r) tmax = fmaxf(tmax, st[nt][r]);
    tmax = fmaxf(tmax, __shfl_xor(tmax, 16, 64));
    tmax = fmaxf(tmax, __shfl_xor(tmax, 32, 64));
    const float mnew = fmaxf(mrow, tmax);
    const float alpha = __expf(mrow - mnew);
    float rs = 0.0f;
#pragma unroll
    for (int nt = 0; nt < 8; ++nt) {
      bf16x4 pd;
#pragma unroll
      for (int r = 0; r < 4; ++r) {
        const float pv = __expf(st[nt][r] - mnew);
        rs += pv;
        pd[r] = (__bf16)pv;
      }
      *(bf16x4*)(&PsT[wave][l15][nt * 16 + quad * 4]) = pd;
    }
    rs += __shfl_xor(rs, 16, 64);
    rs += __shfl_xor(rs, 32, 64);
    lrow = lrow * alpha + rs;
    mrow = mnew;
#pragma unroll
    for (int dt = 0; dt < 4; ++dt) o_[dt] *= alpha;

#pragma unroll
    for (int kc = 0; kc < 4; ++kc) {
      bf16x8 pf = *(const bf16x8*)(&PsT[wave][l15][kc * 32 + quad * 8]);
#pragma unroll
      for (int dt = 0; dt < 4; ++dt) {
        bf16x8 vf = *(const bf16x8*)(&Vts[dt * 16 + l15][kc * 32 + quad * 8]);
        o_[dt] = MFMA16(vf, pf, o_[dt]);
      }
    }
  }

  __syncthreads();
  __bf16 (*Ot)[72] = (__bf16(*)[72])&Vts[0][0];
  const float inv_l = 1.0f / lrow;
#pragma unroll
  for (int dt = 0; dt < 4; ++dt)
#pragma unroll
    for (int r = 0; r < 4; r += 2) {
      bf16x2 pr = { (__bf16)(o_[dt][r] * inv_l),
                    (__bf16)(o_[dt][r + 1] * inv_l) };
      *(bf16x2*)(&Ot[qrow_wl][dt * 16 + quad * 4 + r]) = pr;
    }
  __syncthreads();

  const int b = bh >> 4, h = bh & 15;
#pragma unroll
  for (int t = 0; t < 2; ++t) {
    const int i = t * 256 + tid;
    const int row = i >> 3, c = i & 7;
    f32x4 v = *(const f32x4*)(&Ot[row][c * 8]);
    *(f32x4*)(O + (size_t)(b * 2048 + q0 + row) * 1024 + h * 64 + c * 8) = v;
  }
}

extern "C" void kernel_launch(void* const* d_in, const int* in_sizes, int n_in,
                              void* d_out, int out_size, void* d_ws, size_t ws_size,
                              hipStream_t stream) {
  char* ws = (char*)d_ws;
  int* flag = (int*)ws;
  __bf16* Xc0 = (__bf16*)(ws + (1u << 20));    // 8 MB each (fp32-cvt targets)
  __bf16* Xc1 = (__bf16*)(ws + (9u << 20));
  __bf16* Xc2 = (__bf16*)(ws + (17u << 20));
  __bf16* Wc0 = (__bf16*)(ws + (25u << 20));   // 2 MB each
  __bf16* Wc1 = (__bf16*)(ws + (27u << 20));
  __bf16* Wc2 = (__bf16*)(ws + (29u << 20));
  __bf16* Wc3 = (__bf16*)(ws + (31u << 20));
  __bf16* bc  = (__bf16*)(ws + (33u << 20));
  __bf16* Qw  = (__bf16*)(ws + (34u << 20));   // 8 MB each, [B*H][S][64]
  __bf16* Kw  = (__bf16*)(ws + (42u << 20));
  __bf16* Vw  = (__bf16*)(ws + (50u << 20));
  __bf16* Aw  = (__bf16*)(ws + (58u << 20));   // attn output [4096][1024]

  detect_dtype<<<1, 256, 0, stream>>>((const uint16_t*)d_in[4], flag);

  CvtArgs ca;
  ca.src[0] = d_in[0]; ca.dst[0] = Xc0; ca.n[0] = 4194304;
  ca.src[1] = d_in[1]; ca.dst[1] = Xc1; ca.n[1] = 4194304;
  ca.src[2] = d_in[2]; ca.dst[2] = Xc2; ca.n[2] = 4194304;
  ca.src[3] = d_in[4]; ca.dst[3] = Wc0; ca.n[3] = 1048576;
  ca.src[4] = d_in[5]; ca.dst[4] = Wc1; ca.n[4] = 1048576;
  ca.src[5] = d_in[6]; ca.dst[5] = Wc2; ca.n[5] = 1048576;
  ca.src[6] = d_in[7]; ca.dst[6] = Wc3; ca.n[6] = 1048576;
  ca.src[7] = d_in[8]; ca.dst[7] = bc;  ca.n[7] = 1024;
  convert_all<<<dim3(2048, 8), 256, 0, stream>>>(ca, flag);

  GemmArgs g0;
  g0.A[0] = (const __bf16*)d_in[0]; g0.Acvt[0] = Xc0;
  g0.A[1] = (const __bf16*)d_in[1]; g0.Acvt[1] = Xc1;
  g0.A[2] = (const __bf16*)d_in[2]; g0.Acvt[2] = Xc2;
  g0.W[0] = (const __bf16*)d_in[4]; g0.Wcvt[0] = Wc0;
  g0.W[1] = (const __bf16*)d_in[5]; g0.Wcvt[1] = Wc1;
  g0.W[2] = (const __bf16*)d_in[6]; g0.Wcvt[2] = Wc2;
  g0.C[0] = Qw; g0.scale[0] = 0.125f;
  g0.C[1] = Kw; g0.scale[1] = 1.0f;
  g0.C[2] = Vw; g0.scale[2] = 1.0f;
  g0.bias = nullptr; g0.biascvt = nullptr; g0.flagp = flag; g0.mode = 0;
  gemm_nt<<<dim3(8, 32, 3), 256, 0, stream>>>(g0);

  attn<<<dim3(1024), 256, 0, stream>>>(Qw, Kw, Vw, Aw);

  GemmArgs g1;
  g1.A[0] = Aw; g1.Acvt[0] = Aw;
  g1.A[1] = nullptr; g1.Acvt[1] = nullptr;
  g1.A[2] = nullptr; g1.Acvt[2] = nullptr;
  g1.W[0] = (const __bf16*)d_in[7]; g1.Wcvt[0] = Wc3;
  g1.W[1] = nullptr; g1.Wcvt[1] = nullptr;
  g1.W[2] = nullptr; g1.Wcvt[2] = nullptr;
  g1.C[0] = d_out; g1.scale[0] = 1.0f;
  g1.C[1] = nullptr; g1.scale[1] = 0.f;
  g1.C[2] = nullptr; g1.scale[2] = 0.f;
  g1.bias = (const __bf16*)d_in[8]; g1.biascvt = bc;
  g1.flagp = flag; g1.mode = 1;
  gemm_nt<<<dim3(8, 32, 1), 256, 0, stream>>>(g1);
}